// Round 9
// baseline (231.045 us; speedup 1.0000x reference)
//
#include <hip/hip_runtime.h>
#include <hip/hip_bf16.h>

#define T 2048
#define H 1024
#define IDIM 512
#define E 16
#define TOPK 4
#define NPAIR (T * TOPK)

typedef short bf16x8 __attribute__((ext_vector_type(8)));
typedef float f32x4 __attribute__((ext_vector_type(4)));
typedef unsigned short u16x8 __attribute__((ext_vector_type(8)));

static __device__ __forceinline__ unsigned short f2bf(float f) {
    union { float f; unsigned int u; } v; v.f = f;
    unsigned int r = (v.u + 0x7FFFu + ((v.u >> 16) & 1u)) >> 16;  // RNE
    return (unsigned short)r;
}
static __device__ __forceinline__ float bf2f(unsigned short s) {
    union { unsigned int u; float f; } v; v.u = ((unsigned int)s) << 16;
    return v.f;
}

static __device__ __forceinline__ void async_ld16(const unsigned short* g, unsigned short* l) {
    __builtin_amdgcn_global_load_lds((const __attribute__((address_space(1))) void*)g,
                                     (__attribute__((address_space(3))) void*)l, 16, 0, 0);
}

// ---------------- fp32 -> bf16 weights: 16B-wide stores ----------------
__global__ __launch_bounds__(256) void cvt3_kernel(
    const float* __restrict__ w1, const float* __restrict__ w3, const float* __restrict__ w2,
    unsigned short* __restrict__ d1, unsigned short* __restrict__ d3, unsigned short* __restrict__ d2)
{
    const int n8 = (E * IDIM * H) / 8;      // per-region float8 count (1M)
    int region = blockIdx.x >> 11;          // 3 regions x 2048 blocks
    int bid = blockIdx.x & 2047;
    const float* src = (region == 0) ? w1 : (region == 1) ? w3 : w2;
    unsigned short* dst = (region == 0) ? d1 : (region == 1) ? d3 : d2;
    int i = bid * 256 + threadIdx.x;
    const int stride = 2048 * 256;
#pragma unroll 2
    for (; i < n8; i += stride) {
        float4 a = ((const float4*)src)[2 * i];
        float4 b = ((const float4*)src)[2 * i + 1];
        u16x8 o;
        o[0] = f2bf(a.x); o[1] = f2bf(a.y); o[2] = f2bf(a.z); o[3] = f2bf(a.w);
        o[4] = f2bf(b.x); o[5] = f2bf(b.y); o[6] = f2bf(b.z); o[7] = f2bf(b.w);
        ((u16x8*)dst)[i] = o;
    }
}

// ---------------- Router (fp32 exact) + fused x->bf16 ----------------
// NO global histogram atomics (R4: 8192 device atomics to one line = ~100us).
__global__ __launch_bounds__(256) void router_kernel(
    const float* __restrict__ x, const float* __restrict__ gw,
    int* __restrict__ topk_idx, float* __restrict__ topk_w,
    unsigned short* __restrict__ xb)
{
    int tok = blockIdx.x * 4 + (threadIdx.x >> 6);
    int lane = threadIdx.x & 63;
    if (tok >= T) return;
    const float4* xt4 = (const float4*)(x + (size_t)tok * H);
    float4 xr[4];
#pragma unroll
    for (int j = 0; j < 4; ++j) xr[j] = xt4[lane + j * 64];
    ushort4* xbt = (ushort4*)(xb + (size_t)tok * H);
#pragma unroll
    for (int j = 0; j < 4; ++j) {
        ushort4 o;
        o.x = f2bf(xr[j].x); o.y = f2bf(xr[j].y);
        o.z = f2bf(xr[j].z); o.w = f2bf(xr[j].w);
        xbt[lane + j * 64] = o;
    }
    float logits[E];
#pragma unroll
    for (int e = 0; e < E; ++e) {
        const float4* ge4 = (const float4*)(gw + (size_t)e * H);
        float acc = 0.f;
#pragma unroll
        for (int j = 0; j < 4; ++j) {
            float4 g = ge4[lane + j * 64];
            acc += xr[j].x * g.x + xr[j].y * g.y + xr[j].z * g.z + xr[j].w * g.w;
        }
#pragma unroll
        for (int off = 32; off; off >>= 1) acc += __shfl_xor(acc, off, 64);
        logits[e] = acc;
    }
    if (lane == 0) {
        float m = logits[0];
#pragma unroll
        for (int e = 1; e < E; ++e) m = fmaxf(m, logits[e]);
        float p[E];
#pragma unroll
        for (int e = 0; e < E; ++e) p[e] = __expf(logits[e] - m);
        int sel[TOPK]; float wv[TOPK]; float tot = 0.f;
#pragma unroll
        for (int k = 0; k < TOPK; ++k) {
            int best = 0; float bv = -1.f;
#pragma unroll
            for (int e = 0; e < E; ++e) { if (p[e] > bv) { bv = p[e]; best = e; } }
            sel[k] = best; wv[k] = bv; tot += bv; p[best] = -2.f;
        }
#pragma unroll
        for (int k = 0; k < TOPK; ++k) {
            topk_idx[tok * TOPK + k] = sel[k];
            topk_w[tok * TOPK + k] = wv[k] / tot;
        }
    }
}

// Swizzle (BK=32): global (row, chunk c in 0..3) stored at 16B-slot
//   s = (c + 4*(row&1)) ^ ((row>>1)&7) within 2-row granule (row>>1).
// Read (m, cc): addr_elems = (m>>1)*64 + ((cc + 4*(m&1)) ^ ((m>>1)&7))*8.
// Balance proof: per ds_read_b128 each bank-quad gets exactly 8 of 64 lanes.

// ---------------- GEMM A + integrated routing ----------------
// 128x64 dual tile, BK=32, dbuf 32KB LDS, XCD swizzle. GEMM body FROZEN
// (R0/R5-verified ~45us: schedule-invariant (R1), traffic-bound (R3)).
// NEW: route_build kernel deleted. Each block redundantly computes routing
// from topk_idx via stable index-order ranks (pos = offsets[e] + #{j<i: e_j=e}).
// Atomic-free; ~2-3us prologue; routing LDS aliases staging buffers (dead
// before first async_ld16). n0==0 blocks write inv_pos (exactly once/pair);
// (n0==0,t0==0) blocks publish offsets for gemm_b (idempotent).
__global__ __launch_bounds__(256, 5) void gemm_a_kernel(
    const unsigned short* __restrict__ xb,
    const unsigned short* __restrict__ wb1,
    const unsigned short* __restrict__ wb3,
    const int* __restrict__ topk_idx,
    int* __restrict__ offsets,
    int* __restrict__ inv_pos,
    unsigned short* __restrict__ act)
{
    __shared__ unsigned char SM[32768];
    unsigned short* Xs  = (unsigned short*)SM;             // [2][4096] 16KB (k-loop)
    unsigned short* W1s = (unsigned short*)(SM + 16384);   // [2][2048] 8KB
    unsigned short* W3s = (unsigned short*)(SM + 24576);   // [2][2048] 8KB
    // routing-phase aliases (all dead before staging begins):
    unsigned char*  eb     = SM;                           // [8192] expert ids
    unsigned short* c2d    = (unsigned short*)(SM + 8192); // [257][16] counts/prefix
    int*            offs_l = (int*)(SM + 16448);           // [17]
    unsigned short* tokw   = (unsigned short*)(SM + 16520);// [128] token window

    int bid = blockIdx.x;
    int xcd = bid & 7, s0 = bid >> 3;
    int yz = xcd * 16 + (s0 >> 4);
    int eB = yz >> 3;
    int n0 = (yz & 7) * 64;
    int t0 = (s0 & 15) * 128;

    int tid = threadIdx.x;
    int wave = tid >> 6, lane = tid & 63;

    // ---- pass 1: expert ids -> LDS; per-thread counts packed in 2x u64 (8b fields) ----
    unsigned long long lcA = 0, lcB = 0;
    {
        const int4* tsrc = (const int4*)(topk_idx + tid * 32);
#pragma unroll
        for (int q = 0; q < 8; ++q) {
            int4 v = tsrc[q];
            ((unsigned int*)eb)[tid * 8 + q] =
                (unsigned)v.x | ((unsigned)v.y << 8) | ((unsigned)v.z << 16) | ((unsigned)v.w << 24);
#pragma unroll
            for (int c = 0; c < 4; ++c) {
                int ee = (c == 0) ? v.x : (c == 1) ? v.y : (c == 2) ? v.z : v.w;
                unsigned long long inc = 1ull << ((ee & 7) * 8);
                lcA += (ee < 8) ? inc : 0ull;
                lcB += (ee < 8) ? 0ull : inc;
            }
        }
    }
#pragma unroll
    for (int ee = 0; ee < 8; ++ee) {
        c2d[(tid + 1) * 16 + ee]     = (unsigned short)((lcA >> (ee * 8)) & 0xff);
        c2d[(tid + 1) * 16 + 8 + ee] = (unsigned short)((lcB >> (ee * 8)) & 0xff);
    }
    __syncthreads();
    // ---- column-wise exclusive scan across 256 threads (16 lanes, serial) ----
    if (tid < 16) {
        int run = 0;
        for (int q = 1; q <= 256; ++q) {
            int v = c2d[q * 16 + tid];
            c2d[q * 16 + tid] = (unsigned short)run;
            run += v;
        }
        c2d[tid] = (unsigned short)run;   // histogram total
    }
    __syncthreads();
    if (tid == 0) {
        int s = 0;
#pragma unroll
        for (int ee = 0; ee < E; ++ee) { offs_l[ee] = s; s += c2d[ee]; }
        offs_l[E] = s;
    }
    __syncthreads();
    int beg = offs_l[eB];
    int cnt = offs_l[eB + 1] - beg;
    if (n0 == 0 && t0 == 0 && tid < 17) offsets[tid] = offs_l[tid];  // publish (idempotent x16)
    if (t0 >= cnt) return;   // uniform; all barriers above already passed

    // ---- pass 2: stable ranks; fill this block's token window (+inv_pos once/pair) ----
    {
        int b_ = (tid + 1) * 16;
        unsigned long long r0 = (unsigned long long)c2d[b_ + 0] | ((unsigned long long)c2d[b_ + 1] << 16)
                              | ((unsigned long long)c2d[b_ + 2] << 32) | ((unsigned long long)c2d[b_ + 3] << 48);
        unsigned long long r1 = (unsigned long long)c2d[b_ + 4] | ((unsigned long long)c2d[b_ + 5] << 16)
                              | ((unsigned long long)c2d[b_ + 6] << 32) | ((unsigned long long)c2d[b_ + 7] << 48);
        unsigned long long r2 = (unsigned long long)c2d[b_ + 8] | ((unsigned long long)c2d[b_ + 9] << 16)
                              | ((unsigned long long)c2d[b_ + 10] << 32) | ((unsigned long long)c2d[b_ + 11] << 48);
        unsigned long long r3 = (unsigned long long)c2d[b_ + 12] | ((unsigned long long)c2d[b_ + 13] << 16)
                              | ((unsigned long long)c2d[b_ + 14] << 32) | ((unsigned long long)c2d[b_ + 15] << 48);
        bool wr_inv = (n0 == 0);
#pragma unroll
        for (int q = 0; q < 8; ++q) {
            unsigned int pk = ((unsigned int*)eb)[tid * 8 + q];
#pragma unroll
            for (int c = 0; c < 4; ++c) {
                int ee = (pk >> (c * 8)) & 0xff;
                int grp = ee >> 2, sh = (ee & 3) * 16;
                unsigned long long cur = (grp == 0) ? r0 : (grp == 1) ? r1 : (grp == 2) ? r2 : r3;
                int rk = (int)((cur >> sh) & 0xffffull);
                unsigned long long inc = 1ull << sh;
                r0 += (grp == 0) ? inc : 0ull;
                r1 += (grp == 1) ? inc : 0ull;
                r2 += (grp == 2) ? inc : 0ull;
                r3 += (grp == 3) ? inc : 0ull;
                if (ee == eB) {
                    unsigned int w = (unsigned)(rk - t0);
                    if (w < 128u) {
                        int i = tid * 32 + q * 4 + c;
                        tokw[w] = (unsigned short)(i >> 2);
                        if (wr_inv) inv_pos[i] = beg + rk;
                    }
                }
            }
        }
    }
    __syncthreads();

    // ---- staging source pointers (k-invariant): slot -> (row, chunk) via swizzle ----
    const unsigned short* xg[2];
#pragma unroll
    for (int i = 0; i < 2; ++i) {
        int slot = wave * 128 + i * 64 + lane;
        int g = slot >> 3, sp = (slot & 7) ^ (g & 7);
        int row = g * 2 + (sp >> 2), c = sp & 3;
        int rr = t0 + row; if (rr >= cnt) rr = cnt - 1;
        xg[i] = xb + (size_t)tokw[rr - t0] * H + c * 8;
    }
    const unsigned short* w1g;
    const unsigned short* w3g;
    {
        int slot = wave * 64 + lane;
        int g = slot >> 3, sp = (slot & 7) ^ (g & 7);
        int row = g * 2 + (sp >> 2), c = sp & 3;
        size_t off = (size_t)eB * IDIM * H + (size_t)(n0 + row) * H + c * 8;
        w1g = wb1 + off;
        w3g = wb3 + off;
    }
    __syncthreads();   // routing LDS fully consumed; safe to overwrite via staging

    int wr = wave >> 1, wc = wave & 1;
    int lm = lane & 15, lq = lane >> 4;

    f32x4 acc1[4][2], acc3[4][2];
#pragma unroll
    for (int mi = 0; mi < 4; ++mi)
#pragma unroll
        for (int nj = 0; nj < 2; ++nj) {
            acc1[mi][nj] = (f32x4){0.f, 0.f, 0.f, 0.f};
            acc3[mi][nj] = (f32x4){0.f, 0.f, 0.f, 0.f};
        }

    int aoff[4], boff[2];
#pragma unroll
    for (int mi = 0; mi < 4; ++mi) {
        int m = wr * 64 + mi * 16 + lm;
        int g = m >> 1;
        aoff[mi] = g * 64 + (((lq + ((m & 1) << 2)) ^ (g & 7)) << 3);
    }
#pragma unroll
    for (int nj = 0; nj < 2; ++nj) {
        int n = wc * 32 + nj * 16 + lm;
        int g = n >> 1;
        boff[nj] = g * 64 + (((lq + ((n & 1) << 2)) ^ (g & 7)) << 3);
    }

    // prologue
#pragma unroll
    for (int i = 0; i < 2; ++i) async_ld16(xg[i], Xs + (wave * 128 + i * 64) * 8);
    async_ld16(w1g, W1s + wave * 512);
    async_ld16(w3g, W3s + wave * 512);

    const int NK = H / 32;
    for (int kk = 0; kk < NK; ++kk) {
        int cur = kk & 1;
        __syncthreads();
        if (kk + 1 < NK) {
            int nxt = cur ^ 1;
            int k1 = (kk + 1) * 32;
#pragma unroll
            for (int i = 0; i < 2; ++i)
                async_ld16(xg[i] + k1, Xs + nxt * 4096 + (wave * 128 + i * 64) * 8);
            async_ld16(w1g + k1, W1s + nxt * 2048 + wave * 512);
            async_ld16(w3g + k1, W3s + nxt * 2048 + wave * 512);
        }
        bf16x8 af[4], b1[2], b3[2];
#pragma unroll
        for (int mi = 0; mi < 4; ++mi) af[mi] = *(const bf16x8*)(Xs + cur * 4096 + aoff[mi]);
#pragma unroll
        for (int nj = 0; nj < 2; ++nj) {
            b1[nj] = *(const bf16x8*)(W1s + cur * 2048 + boff[nj]);
            b3[nj] = *(const bf16x8*)(W3s + cur * 2048 + boff[nj]);
        }
#pragma unroll
        for (int mi = 0; mi < 4; ++mi)
#pragma unroll
            for (int nj = 0; nj < 2; ++nj) {
                acc1[mi][nj] = __builtin_amdgcn_mfma_f32_16x16x32_bf16(af[mi], b1[nj], acc1[mi][nj], 0, 0, 0);
                acc3[mi][nj] = __builtin_amdgcn_mfma_f32_16x16x32_bf16(af[mi], b3[nj], acc3[mi][nj], 0, 0, 0);
            }
    }
#pragma unroll
    for (int mi = 0; mi < 4; ++mi) {
#pragma unroll
        for (int r = 0; r < 4; ++r) {
            int trow = t0 + wr * 64 + mi * 16 + lq * 4 + r;
            if (trow < cnt) {
                size_t base = (size_t)(beg + trow) * IDIM + n0 + wc * 32 + lm;
#pragma unroll
                for (int nj = 0; nj < 2; ++nj) {
                    float h1 = acc1[mi][nj][r];
                    float sg = h1 / (1.f + __expf(-h1));
                    act[base + nj * 16] = f2bf(sg * acc3[mi][nj][r]);
                }
            }
        }
    }
}

// ---------------- GEMM B: outp_bf16[pos,:] = act @ w2^T ----------------
// 128x64 tile, BK=32, dbuf 24KB LDS, XCD swizzle. FROZEN (R0/R5-verified).
__global__ __launch_bounds__(256, 5) void gemm_b_kernel(
    const unsigned short* __restrict__ act,
    const unsigned short* __restrict__ wb2,
    const int* __restrict__ offsets,
    unsigned short* __restrict__ outp)
{
    __shared__ unsigned short As[2][128 * 32];
    __shared__ unsigned short W2s[2][64 * 32];

    int bid = blockIdx.x;
    int xcd = bid & 7, s0 = bid >> 3;
    int yz = xcd * 32 + (s0 >> 4);
    int e = yz >> 4;
    int h0 = (yz & 15) * 64;
    int t0 = (s0 & 15) * 128;

    int beg = offsets[e];
    int cnt = offsets[e + 1] - beg;
    if (t0 >= cnt) return;

    int tid = threadIdx.x;
    int wave = tid >> 6, lane = tid & 63;

    const unsigned short* ag[2];
#pragma unroll
    for (int i = 0; i < 2; ++i) {
        int slot = wave * 128 + i * 64 + lane;
        int g = slot >> 3, sp = (slot & 7) ^ (g & 7);
        int row = g * 2 + (sp >> 2), c = sp & 3;
        int ar = beg + t0 + row; if (ar > NPAIR - 1) ar = NPAIR - 1;
        ag[i] = act + (size_t)ar * IDIM + c * 8;
    }
    const unsigned short* w2g;
    {
        int slot = wave * 64 + lane;
        int g = slot >> 3, sp = (slot & 7) ^ (g & 7);
        int row = g * 2 + (sp >> 2), c = sp & 3;
        w2g = wb2 + (size_t)e * H * IDIM + (size_t)(h0 + row) * IDIM + c * 8;
    }

    int wr = wave >> 1, wc = wave & 1;
    int lm = lane & 15, lq = lane >> 4;

    f32x4 acc[4][2];
#pragma unroll
    for (int mi = 0; mi < 4; ++mi)
#pragma unroll
        for (int nj = 0; nj < 2; ++nj) acc[mi][nj] = (f32x4){0.f, 0.f, 0.f, 0.f};

    int aoff[4], boff[2];
#pragma unroll
    for (int mi = 0; mi < 4; ++mi) {
        int m = wr * 64 + mi * 16 + lm;
        int g = m >> 1;
        aoff[mi] = g * 64 + (((lq + ((m & 1) << 2)) ^ (g & 7)) << 3);
    }
#pragma unroll
    for (int nj = 0; nj < 2; ++nj) {
        int n = wc * 32 + nj * 16 + lm;
        int g = n >> 1;
        boff[nj] = g * 64 + (((lq + ((n & 1) << 2)) ^ (g & 7)) << 3);
    }

#pragma unroll
    for (int i = 0; i < 2; ++i) async_ld16(ag[i], &As[0][(wave * 128 + i * 64) * 8]);
    async_ld16(w2g, &W2s[0][wave * 512]);

    const int NK = IDIM / 32;
    for (int kk = 0; kk < NK; ++kk) {
        int cur = kk & 1;
        __syncthreads();
        if (kk + 1 < NK) {
            int nxt = cur ^ 1;
            int k1 = (kk + 1) * 32;
#pragma unroll
            for (int i = 0; i < 2; ++i) async_ld16(ag[i] + k1, &As[nxt][(wave * 128 + i * 64) * 8]);
            async_ld16(w2g + k1, &W2s[nxt][wave * 512]);
        }
        bf16x8 af[4], bfr[2];
#pragma unroll
        for (int mi = 0; mi < 4; ++mi) af[mi] = *(const bf16x8*)&As[cur][aoff[mi]];
#pragma unroll
        for (int nj = 0; nj < 2; ++nj) bfr[nj] = *(const bf16x8*)&W2s[cur][boff[nj]];
#pragma unroll
        for (int mi = 0; mi < 4; ++mi)
#pragma unroll
            for (int nj = 0; nj < 2; ++nj)
                acc[mi][nj] = __builtin_amdgcn_mfma_f32_16x16x32_bf16(af[mi], bfr[nj], acc[mi][nj], 0, 0, 0);
    }
#pragma unroll
    for (int mi = 0; mi < 4; ++mi) {
#pragma unroll
        for (int r = 0; r < 4; ++r) {
            int trow = t0 + wr * 64 + mi * 16 + lq * 4 + r;
            if (trow < cnt) {
                unsigned short* orow = outp + (size_t)(beg + trow) * H + h0 + wc * 32 + lm;
#pragma unroll
                for (int nj = 0; nj < 2; ++nj) orow[nj * 16] = f2bf(acc[mi][nj][r]);
            }
        }
    }
}

// ---------------- Combine ----------------
__global__ __launch_bounds__(256) void combine_kernel(
    const unsigned short* __restrict__ outp, const int* __restrict__ inv_pos,
    const float* __restrict__ topk_w, float* __restrict__ out)
{
    int gid = blockIdx.x * 256 + threadIdx.x;
    int t = gid >> 8;
    int c4 = gid & 255;
    float4 a = make_float4(0.f, 0.f, 0.f, 0.f);
#pragma unroll
    for (int k = 0; k < TOPK; ++k) {
        int pos = inv_pos[t * TOPK + k];
        float w = topk_w[t * TOPK + k];
        ushort4 v = ((const ushort4*)(outp + (size_t)pos * H))[c4];
        a.x += w * bf2f(v.x); a.y += w * bf2f(v.y);
        a.z += w * bf2f(v.z); a.w += w * bf2f(v.w);
    }
    *(float4*)(out + (size_t)t * H + c4 * 4) = a;
}

extern "C" void kernel_launch(void* const* d_in, const int* in_sizes, int n_in,
                              void* d_out, int out_size, void* d_ws, size_t ws_size,
                              hipStream_t stream)
{
    const float* x  = (const float*)d_in[0];
    const float* gw = (const float*)d_in[1];
    const float* w1 = (const float*)d_in[2];
    const float* w3 = (const float*)d_in[3];
    const float* w2 = (const float*)d_in[4];
    float* out = (float*)d_out;

    char* ws = (char*)d_ws;
    int*   offsets    = (int*)(ws + 128);
    int*   topk_idx   = (int*)(ws + 1024);
    float* topk_w     = (float*)(ws + 33792);
    int*   inv_pos    = (int*)(ws + 99328);
    unsigned short* xb  = (unsigned short*)(ws + 262144);    // 4 MB
    unsigned short* wb1 = (unsigned short*)(ws + 8388608);   // 16 MB
    unsigned short* wb3 = (unsigned short*)(ws + 25165824);  // 16 MB
    unsigned short* wb2 = (unsigned short*)(ws + 41943040);  // 16 MB
    unsigned short* act = (unsigned short*)(ws + 58720256);  // 8 MB
    unsigned short* outp = (unsigned short*)(ws + 8388608);  // 16 MB, aliases wb1 (dead after gemm_a)

    router_kernel<<<T / 4, 256, 0, stream>>>(x, gw, topk_idx, topk_w, xb);
    cvt3_kernel<<<3 * 2048, 256, 0, stream>>>(w1, w3, w2, wb1, wb3, wb2);

    gemm_a_kernel<<<2048, 256, 0, stream>>>(xb, wb1, wb3, topk_idx, offsets, inv_pos, act);
    gemm_b_kernel<<<4096, 256, 0, stream>>>(act, wb2, offsets, outp);
    combine_kernel<<<(T * H / 4) / 256, 256, 0, stream>>>(outp, inv_pos, topk_w, out);
}